// Round 4
// baseline (343.068 us; speedup 1.0000x reference)
//
#include <hip/hip_runtime.h>

#define T      792
#define ND     99
#define NL     16
#define KBLK   25        // 25 k-blocks of 32 (K padded 792 -> 800)
#define BATCH  65536
#define NTILES (BATCH / 16)   // 4096 tiles of 16 batch rows

typedef __attribute__((ext_vector_type(8))) short  short8;   // 8 bf16 in 4 VGPRs
typedef __attribute__((ext_vector_type(4))) float  float4v;

// f32 -> bf16 round-to-nearest-even
__device__ inline unsigned short f2bf(float x) {
    union { float f; unsigned u; } c; c.f = x;
    return (unsigned short)((c.u + 0x7FFFu + ((c.u >> 16) & 1u)) >> 16);
}

// Wave pairs split K (even wave kb 0..12, odd 13..24), combine via LDS.
// B one-hot built on the fly from nibble-packed t2l. This round: manual 2-deep
// software pipeline (prefetch next a0/a1/d before consuming current) + nt loads
// on the read-once pred stream.
__global__ __launch_bounds__(256) void llb_mfma(
    const float* __restrict__ pred,   // [BATCH, 792]
    const float* __restrict__ dem,    // [BATCH, 99]
    const int*   __restrict__ t2l,    // [792]
    const float* __restrict__ cap,    // [16]
    float* __restrict__ partial)      // [NTILES]
{
    __shared__ unsigned packed[KBLK * 4];   // word w = links of k=8w..8w+7 (4b each)
    __shared__ float4v  comb[2][64];        // odd-wave accumulator handoff

    const int lane = threadIdx.x & 63;
    const int wid  = threadIdx.x >> 6;
    const int g    = lane >> 4;             // k-group 0..3
    const int n    = lane & 15;             // col (link) / A-row-in-tile

    if (threadIdx.x < KBLK * 4) {
        const int w = threadIdx.x;
        unsigned u = 0;
#pragma unroll
        for (int j = 0; j < 8; ++j) {
            const int k = w * 8 + j;
            const unsigned link = (k < T) ? (unsigned)t2l[k] : 0u;  // pad unused (d=0)
            u |= link << (4 * j);
        }
        packed[w] = u;
    }
    __syncthreads();

    const int tile   = (int)blockIdx.x * 2 + (wid >> 1);  // 2048 blocks * 2 tiles
    const int kb0    = (wid & 1) ? 13 : 0;
    const int kb1    = (wid & 1) ? KBLK : 13;
    const int arow_i = tile * 16 + n;                     // A fragment: m = lane&15
    const float* __restrict__ arow = pred + (size_t)arow_i * T;
    const float* __restrict__ drow = dem  + (size_t)arow_i * ND;

    // ---- software pipeline: stage 0 prefetch ----
    int idx = kb0 * 4 + g;                      // packed-word index == demand index
    int k0  = idx * 8;
    int kc  = (k0 <= T - 8) ? k0 : (T - 8);
    float4v a0c = __builtin_nontemporal_load((const float4v*)(arow + kc));
    float4v a1c = __builtin_nontemporal_load((const float4v*)(arow + kc + 4));
    float   dc  = (idx < ND) ? drow[idx] : 0.f;

    float4v acc = {0.f, 0.f, 0.f, 0.f};
    for (int kb = kb0; kb < kb1; ++kb) {
        // prefetch next iteration (re-loads current on the last trip; harmless)
        const int kbn  = (kb + 1 < kb1) ? kb + 1 : kb;
        const int idxn = kbn * 4 + g;
        const int k0n  = idxn * 8;
        const int kcn  = (k0n <= T - 8) ? k0n : (T - 8);
        const float4v a0n = __builtin_nontemporal_load((const float4v*)(arow + kcn));
        const float4v a1n = __builtin_nontemporal_load((const float4v*)(arow + kcn + 4));
        const float   dn  = (idxn < ND) ? drow[idxn] : 0.f;

        const unsigned u = packed[idx];          // broadcast within 16-lane group

        union { unsigned short us[8]; short8 v; } af, bf;
        af.us[0] = f2bf(a0c.x * dc); af.us[1] = f2bf(a0c.y * dc);
        af.us[2] = f2bf(a0c.z * dc); af.us[3] = f2bf(a0c.w * dc);
        af.us[4] = f2bf(a1c.x * dc); af.us[5] = f2bf(a1c.y * dc);
        af.us[6] = f2bf(a1c.z * dc); af.us[7] = f2bf(a1c.w * dc);
#pragma unroll
        for (int j = 0; j < 8; ++j)
            bf.us[j] = (((u >> (4 * j)) & 15u) == (unsigned)n)
                           ? (unsigned short)0x3F80 : (unsigned short)0;

        acc = __builtin_amdgcn_mfma_f32_16x16x32_bf16(af.v, bf.v, acc, 0, 0, 0);

        a0c = a0n; a1c = a1n; dc = dn; idx = idxn;
    }

    // Combine K-split halves: odd wave hands its acc to its even partner.
    if (wid & 1) comb[wid >> 1][lane] = acc;
    __syncthreads();
    if (!(wid & 1)) {
        const float4v o = comb[wid >> 1][lane];
        const float invcap = 1.0f / (cap[n] + 1e-8f);
        // C/D layout (HW-verified): col = lane&15 (= link), row = (lane>>4)*4 + reg.
        float lsum = 0.f;
#pragma unroll
        for (int r = 0; r < 4; ++r) {
            const float uu = (acc[r] + o[r]) * invcap;
            float s = uu, q = uu * uu, m = uu;
#pragma unroll
            for (int off = 8; off >= 1; off >>= 1) {
                s += __shfl_xor(s, off, 16);
                q += __shfl_xor(q, off, 16);
                const float om = __shfl_xor(m, off, 16);
                m = m > om ? m : om;
            }
            if (n == 0) {
                const float var = (q - s * s * (1.0f / 16.0f)) * (1.0f / 15.0f);  // ddof=1
                lsum += var + 0.5f * m;
            }
        }
        lsum += __shfl_xor(lsum, 16, 64);   // fold the 4 group leaders
        lsum += __shfl_xor(lsum, 32, 64);
        if (lane == 0) partial[tile] = lsum;
    }
}

__global__ __launch_bounds__(256) void llb_reduce(
    const float* __restrict__ partial, float* __restrict__ out)
{
    float s = 0.f;
    for (int i = threadIdx.x; i < NTILES; i += 256) s += partial[i];
#pragma unroll
    for (int off = 32; off >= 1; off >>= 1) s += __shfl_xor(s, off, 64);
    __shared__ float red[4];
    if ((threadIdx.x & 63) == 0) red[threadIdx.x >> 6] = s;
    __syncthreads();
    if (threadIdx.x == 0)
        out[0] = (red[0] + red[1] + red[2] + red[3]) * (1.0f / (float)BATCH);
}

extern "C" void kernel_launch(void* const* d_in, const int* in_sizes, int n_in,
                              void* d_out, int out_size, void* d_ws, size_t ws_size,
                              hipStream_t stream) {
    const float* pred = (const float*)d_in[0];
    const float* dem  = (const float*)d_in[1];
    const int*   t2l  = (const int*)d_in[2];
    const float* cap  = (const float*)d_in[3];
    float* out     = (float*)d_out;
    float* partial = (float*)d_ws;            // 4096 floats = 16 KB scratch

    llb_mfma<<<NTILES / 2, 256, 0, stream>>>(pred, dem, t2l, cap, partial);
    llb_reduce<<<1, 256, 0, stream>>>(partial, out);
}

// Round 5
// 308.715 us; speedup vs baseline: 1.1113x; 1.1113x over previous
//
#include <hip/hip_runtime.h>

#define T      792
#define ND     99
#define NL     16
#define KBLK   25        // 25 k-blocks of 32 (K padded 792 -> 800)
#define BATCH  65536
#define NTILES (BATCH / 16)   // 4096 tiles of 16 batch rows

typedef __attribute__((ext_vector_type(8))) short  short8;   // 8 bf16 in 4 VGPRs
typedef __attribute__((ext_vector_type(4))) float  float4v;

// f32 -> bf16 round-to-nearest-even
__device__ inline unsigned short f2bf(float x) {
    union { float f; unsigned u; } c; c.f = x;
    return (unsigned short)((c.u + 0x7FFFu + ((c.u >> 16) & 1u)) >> 16);
}

// Fully-unrolled K-half with depth-4 circular register prefetch.
// Normal (cached) loads: ~half of pred hits L3 across replays (R1 FETCH evidence).
template<int KB0, int NKB>
__device__ __forceinline__ float4v k_half(
    const float* __restrict__ arow, const float* __restrict__ drow,
    const unsigned* __restrict__ packed, const int g, const int n)
{
    constexpr int PF = 4;
    float4v A0[PF], A1[PF];
    float   D[PF];
#pragma unroll
    for (int p = 0; p < PF; ++p) {
        const int idx = (KB0 + p) * 4 + g;
        const int k0  = idx * 8;
        const int kc  = (k0 <= T - 8) ? k0 : (T - 8);
        A0[p] = *(const float4v*)(arow + kc);
        A1[p] = *(const float4v*)(arow + kc + 4);
        D[p]  = (idx < ND) ? drow[idx] : 0.f;     // only idx==99 (pad block) clamps
    }
    float4v acc = {0.f, 0.f, 0.f, 0.f};
#pragma unroll
    for (int i = 0; i < NKB; ++i) {
        const int slot = i & (PF - 1);            // static after full unroll
        const int idx  = (KB0 + i) * 4 + g;
        const unsigned u = packed[idx];           // LDS broadcast within 16-lane group

        const float4v a0 = A0[slot], a1 = A1[slot];
        const float   d  = D[slot];

        // refill freed slot: keeps ~9-12 loads outstanding in steady state
        if (i + PF < NKB) {
            const int idx2 = (KB0 + i + PF) * 4 + g;
            const int k02  = idx2 * 8;
            const int kc2  = (k02 <= T - 8) ? k02 : (T - 8);
            A0[slot] = *(const float4v*)(arow + kc2);
            A1[slot] = *(const float4v*)(arow + kc2 + 4);
            D[slot]  = (idx2 < ND) ? drow[idx2] : 0.f;
        }

        union { unsigned short us[8]; short8 v; } af, bf;
        af.us[0] = f2bf(a0.x * d); af.us[1] = f2bf(a0.y * d);
        af.us[2] = f2bf(a0.z * d); af.us[3] = f2bf(a0.w * d);
        af.us[4] = f2bf(a1.x * d); af.us[5] = f2bf(a1.y * d);
        af.us[6] = f2bf(a1.z * d); af.us[7] = f2bf(a1.w * d);
#pragma unroll
        for (int j = 0; j < 8; ++j)
            bf.us[j] = (((u >> (4 * j)) & 15u) == (unsigned)n)
                           ? (unsigned short)0x3F80 : (unsigned short)0;

        acc = __builtin_amdgcn_mfma_f32_16x16x32_bf16(af.v, bf.v, acc, 0, 0, 0);
    }
    return acc;
}

__global__ __launch_bounds__(256) void llb_mfma(
    const float* __restrict__ pred,   // [BATCH, 792]
    const float* __restrict__ dem,    // [BATCH, 99]
    const int*   __restrict__ t2l,    // [792]
    const float* __restrict__ cap,    // [16]
    float* __restrict__ partial)      // [NTILES]
{
    __shared__ unsigned packed[KBLK * 4];   // word w = links of k=8w..8w+7 (4b each)
    __shared__ float4v  comb[2][64];        // odd-wave accumulator handoff

    const int lane = threadIdx.x & 63;
    const int wid  = threadIdx.x >> 6;
    const int g    = lane >> 4;             // k-group 0..3
    const int n    = lane & 15;             // col (link) / A-row-in-tile

    if (threadIdx.x < KBLK * 4) {
        const int w = threadIdx.x;
        unsigned u = 0;
#pragma unroll
        for (int j = 0; j < 8; ++j) {
            const int k = w * 8 + j;
            const unsigned link = (k < T) ? (unsigned)t2l[k] : 0u;  // pad unused (d=0)
            u |= link << (4 * j);
        }
        packed[w] = u;
    }
    __syncthreads();

    const int tile   = (int)blockIdx.x * 2 + (wid >> 1);  // 2048 blocks * 2 tiles
    const int arow_i = tile * 16 + n;                     // A fragment: m = lane&15
    const float* __restrict__ arow = pred + (size_t)arow_i * T;
    const float* __restrict__ drow = dem  + (size_t)arow_i * ND;

    const float4v acc = (wid & 1)
        ? k_half<13, 12>(arow, drow, packed, g, n)
        : k_half<0, 13>(arow, drow, packed, g, n);

    // Combine K-split halves: odd wave hands its acc to its even partner.
    if (wid & 1) comb[wid >> 1][lane] = acc;
    __syncthreads();
    if (!(wid & 1)) {
        const float4v o = comb[wid >> 1][lane];
        const float invcap = 1.0f / (cap[n] + 1e-8f);
        // C/D layout (HW-verified): col = lane&15 (= link), row = (lane>>4)*4 + reg.
        float lsum = 0.f;
#pragma unroll
        for (int r = 0; r < 4; ++r) {
            const float uu = (acc[r] + o[r]) * invcap;
            float s = uu, q = uu * uu, m = uu;
#pragma unroll
            for (int off = 8; off >= 1; off >>= 1) {
                s += __shfl_xor(s, off, 16);
                q += __shfl_xor(q, off, 16);
                const float om = __shfl_xor(m, off, 16);
                m = m > om ? m : om;
            }
            if (n == 0) {
                const float var = (q - s * s * (1.0f / 16.0f)) * (1.0f / 15.0f);  // ddof=1
                lsum += var + 0.5f * m;
            }
        }
        lsum += __shfl_xor(lsum, 16, 64);   // fold the 4 group leaders
        lsum += __shfl_xor(lsum, 32, 64);
        if (lane == 0) partial[tile] = lsum;
    }
}

__global__ __launch_bounds__(256) void llb_reduce(
    const float* __restrict__ partial, float* __restrict__ out)
{
    float s = 0.f;
    for (int i = threadIdx.x; i < NTILES; i += 256) s += partial[i];
#pragma unroll
    for (int off = 32; off >= 1; off >>= 1) s += __shfl_xor(s, off, 64);
    __shared__ float red[4];
    if ((threadIdx.x & 63) == 0) red[threadIdx.x >> 6] = s;
    __syncthreads();
    if (threadIdx.x == 0)
        out[0] = (red[0] + red[1] + red[2] + red[3]) * (1.0f / (float)BATCH);
}

extern "C" void kernel_launch(void* const* d_in, const int* in_sizes, int n_in,
                              void* d_out, int out_size, void* d_ws, size_t ws_size,
                              hipStream_t stream) {
    const float* pred = (const float*)d_in[0];
    const float* dem  = (const float*)d_in[1];
    const int*   t2l  = (const int*)d_in[2];
    const float* cap  = (const float*)d_in[3];
    float* out     = (float*)d_out;
    float* partial = (float*)d_ws;            // 4096 floats = 16 KB scratch

    llb_mfma<<<NTILES / 2, 256, 0, stream>>>(pred, dem, t2l, cap, partial);
    llb_reduce<<<1, 256, 0, stream>>>(partial, out);
}